// Round 15
// baseline (576.126 us; speedup 1.0000x reference)
//
#include <hip/hip_runtime.h>
#include <hip/hip_bf16.h>

#define ND 50000
#define NS 30000
#define NE 1000000
#define EL 200000
#define NTOT (NS + ND)          // 80000
#define SCAN_BLK ((NTOT + 1023) / 1024)   // 79

#define RANK_BLKS ((NE + 255) / 256)      // 3907
#define TRW4_BLKS 1024                    // 4 mats * 65536 / 256
#define COMP_BLKS 64
#define BIAS_BLKS 2
#define WROLE_BLKS (TRW4_BLKS + COMP_BLKS + BIAS_BLKS)   // 1090
#define RW_GRP 977                        // groups of (4 rank + 1 wrole)
#define RW_BLKS (5 * RW_GRP + (WROLE_BLKS - RW_GRP))     // 4998

#define NB_D (391 * 2)                    // 782
#define NB_S (235 * 2)                    // 470
#define GEMM1_BLKS (2 * NB_D + 2 * NB_S)  // 2504
#define PG_GRP 1252                       // groups of (3 place + 2 gemm)
#define PG_BLKS (5 * PG_GRP + (RANK_BLKS - 3 * PG_GRP))  // 6411

typedef short short8 __attribute__((ext_vector_type(8)));
typedef float f32x4 __attribute__((ext_vector_type(4)));

__device__ __forceinline__ float b2f(unsigned short u) {
    union { unsigned int i; float f; } c; c.i = ((unsigned int)u) << 16; return c.f;
}
__device__ __forceinline__ unsigned short f2b(float f) {
    __hip_bfloat16 h = __float2bfloat16(f);   // RNE
    union { __hip_bfloat16 h; unsigned short u; } c; c.h = h; return c.u;
}

__device__ __forceinline__ void gload_lds16(const unsigned short* g, unsigned short* l) {
    __builtin_amdgcn_global_load_lds(
        (const __attribute__((address_space(1))) unsigned int*)g,
        (__attribute__((address_space(3))) unsigned int*)l, 16, 0, 0);
}

struct WAll {
    const float* w1[4];      // Wl1_ds, Wr1_ds, Wl1_sd, Wr1_sd  -> WT[0..3]
    const float* w2[4];      // Wl2_ds, Wr2_ds, Wl2_sd, Wr2_sd  -> WT[4..7] composed
    const float* wdec1;
    const float* bl2_ds;
    const float* bl2_sd;
};

// ---------------- rank_w: rank atomics (the ~110us fabric-atomic floor) || W prep ----------------
// W-prep roles are light (1090 blocks, streaming) -> minimal interference with rank.
// Decoder fold (layer 2 linear):
//   Ps = aggs@(Wl2_ds@Wbot) + zs1@(Wr2_ds@Wbot) + bl2_ds@Wbot
//   Pd = aggd@(Wl2_sd@Wtop) + zd1@(Wr2_sd@Wtop) + bl2_sd@Wtop
__global__ __launch_bounds__(256) void rank_w(const int* __restrict__ esrc,
                                              const int* __restrict__ edst,
                                              int* cnt_drug, int* cnt_dis,
                                              unsigned short* __restrict__ rank_sd,
                                              unsigned short* __restrict__ rank_ds,
                                              WAll wa,
                                              unsigned short* __restrict__ Wt,
                                              float* __restrict__ cbuf) {
    const int b = blockIdx.x, t = threadIdx.x;
    int role, idx;
    if (b < 5 * RW_GRP) {
        int g = b / 5, r = b - g * 5;
        if (r < 4) { role = 0; idx = g * 4 + r; }
        else       { role = 1; idx = g; }
    } else {
        role = 1; idx = RW_GRP + (b - 5 * RW_GRP);
    }

    if (role == 0) {
        int i = idx * 256 + t;
        if (i < NE) {
            int s = esrc[i], d = edst[i];
            rank_ds[i] = (unsigned short)atomicAdd(&cnt_dis[d], 1);
            rank_sd[i] = (unsigned short)atomicAdd(&cnt_drug[s], 1);
        }
        return;
    }
    if (idx < TRW4_BLKS) {
        // layer-1 weights: plain transpose to bf16 [n][k]
        int o = idx * 256 + t;
        int mat = o >> 16, i2 = o & 65535;
        int n = i2 >> 8, k = i2 & 255;
        Wt[o] = f2b(wa.w1[mat][k * 256 + n]);
    } else if (idx < TRW4_BLKS + COMP_BLKS) {
        // composed weights: CT[n][k] = sum_j W2[k][j] * Wd[j][n]
        int ci = idx - TRW4_BLKS;
        int mat = ci >> 4;
        int k0 = (ci & 15) * 16;
        const float* W2 = wa.w2[mat];
        const float* Wd = wa.wdec1 + ((mat < 2) ? 65536 : 0);
        float acc[16] = {};
        const int n = t;
        for (int j = 0; j < 256; ++j) {
            float wd = Wd[j * 256 + n];
#pragma unroll
            for (int k = 0; k < 16; ++k) acc[k] += W2[(k0 + k) * 256 + j] * wd;
        }
        unsigned short* dst = Wt + (size_t)(4 + mat) * 65536 + n * 256 + k0;
#pragma unroll
        for (int k = 0; k < 16; ++k) dst[k] = f2b(acc[k]);
    } else {
        int bi = idx - TRW4_BLKS - COMP_BLKS;   // 0 or 1
        const float* bsrc = bi ? wa.bl2_sd : wa.bl2_ds;
        const float* Wd = wa.wdec1 + (bi ? 0 : 65536);
        float acc = 0.f;
        const int n = t;
        for (int j = 0; j < 256; ++j) acc += bsrc[j] * Wd[j * 256 + n];
        cbuf[bi * 256 + n] = acc;
    }
}

// ---------------- scan ----------------

__global__ __launch_bounds__(256) void scan_part(const int* __restrict__ cnt,
                                                 int* __restrict__ bsum) {
    __shared__ int red[4];
    int t = threadIdx.x, lane = t & 63, wid = t >> 6;
    int base = blockIdx.x * 1024 + t * 4;
    int s = 0;
    if (base < NTOT) {
        int4 c = *reinterpret_cast<const int4*>(cnt + base);
        s = c.x + c.y + c.z + c.w;
    }
#pragma unroll
    for (int off = 32; off; off >>= 1) s += __shfl_down(s, off);
    if (lane == 0) red[wid] = s;
    __syncthreads();
    if (t == 0) bsum[blockIdx.x] = red[0] + red[1] + red[2] + red[3];
}

__global__ void scan_top(int* bsum, int nb) {
    int lane = threadIdx.x;
    int a0 = lane < nb ? bsum[lane] : 0;
    int a1 = (64 + lane) < nb ? bsum[64 + lane] : 0;
    int i0 = a0, i1 = a1;
#pragma unroll
    for (int off = 1; off < 64; off <<= 1) {
        int t0 = __shfl_up(i0, off);
        int t1 = __shfl_up(i1, off);
        if (lane >= off) { i0 += t0; i1 += t1; }
    }
    int tot0 = __shfl(i0, 63);
    if (lane < nb) bsum[lane] = i0 - a0;
    if (64 + lane < nb) bsum[64 + lane] = tot0 + i1 - a1;
}

__global__ __launch_bounds__(256) void scan_emit(const int* __restrict__ cnt,
                                                 const int* __restrict__ boff,
                                                 int* __restrict__ row_dis,
                                                 int* __restrict__ row_drug,
                                                 float* __restrict__ inv_dis,
                                                 float* __restrict__ inv_drug) {
    __shared__ int wsum[4];
    int t = threadIdx.x, lane = t & 63, wid = t >> 6;
    int base = blockIdx.x * 1024 + t * 4;
    int4 c = make_int4(0, 0, 0, 0);
    if (base < NTOT) c = *reinterpret_cast<const int4*>(cnt + base);
    int sl = c.x + c.y + c.z + c.w;
    int sc = sl;
#pragma unroll
    for (int off = 1; off < 64; off <<= 1) {
        int tv = __shfl_up(sc, off);
        if (lane >= off) sc += tv;
    }
    if (lane == 63) wsum[wid] = sc;
    __syncthreads();
    int woff = 0;
    for (int w2 = 0; w2 < wid; ++w2) woff += wsum[w2];
    int run = boff[blockIdx.x] + woff + (sc - sl);
    int cc[4] = { c.x, c.y, c.z, c.w };
    if (base < NTOT) {
#pragma unroll
        for (int k = 0; k < 4; ++k) {
            int i = base + k;
            float iv = 1.0f / (float)(cc[k] > 1 ? cc[k] : 1);
            if (i < NS) { row_dis[i] = run; inv_dis[i] = iv; }
            else        { row_drug[i - NS] = run - NE; inv_drug[i - NS] = iv; }
            run += cc[k];
        }
    }
    if (blockIdx.x == 0 && t == 0) { row_dis[NS] = NE; row_drug[ND] = NE; }
}

// ---------------- place_gemm: place scatter (latency/write-bound) || layer-1 GEMMs ----------------
// (S.X)@W = S.(X@W): layer-1 products need only X + Wt[0..3] (ready after rank_w).
// place is scatter-bound with idle VALU/MFMA -> gemm1's MFMA work hides under it.
__global__ __launch_bounds__(256) void place_gemm(const int* __restrict__ esrc,
                                                  const int* __restrict__ edst,
                                                  const int* __restrict__ row_drug,
                                                  const int* __restrict__ row_dis,
                                                  const unsigned short* __restrict__ rank_sd,
                                                  const unsigned short* __restrict__ rank_ds,
                                                  unsigned short* __restrict__ val_sd,
                                                  unsigned short* __restrict__ val_ds,
                                                  const float* __restrict__ xd,
                                                  const float* __restrict__ xs,
                                                  const unsigned short* __restrict__ Wt,
                                                  unsigned short* __restrict__ PA0,
                                                  unsigned short* __restrict__ RA3,
                                                  unsigned short* __restrict__ PB2,
                                                  unsigned short* __restrict__ RB1) {
    __shared__ unsigned short As[128 * 64];
    __shared__ unsigned short Bs[128 * 64];
    const int b = blockIdx.x, t = threadIdx.x;
    int role, idx;
    if (b < 5 * PG_GRP) {
        int g = b / 5, r = b - g * 5;
        if (r < 3) { role = 0; idx = g * 3 + r; }
        else       { role = 1; idx = g * 2 + r - 3; }
    } else {
        role = 0; idx = 3 * PG_GRP + (b - 5 * PG_GRP);
    }

    if (role == 0) {
        int i = idx * 256 + t;
        if (i < NE) {
            int s = esrc[i], d = edst[i];
            val_ds[row_dis[d] + (int)rank_ds[i]] = (unsigned short)s;
            val_sd[row_drug[s] + (int)rank_sd[i]] = (unsigned short)d;
        }
        return;
    }

    // ---- gemm role: 4 single-product segments, A reg-staged from fp32 X ----
    int gi = idx;
    const float* Xf; const unsigned short* Bt; unsigned short* C; int M;
    if (gi < NB_D)            { Xf = xd; Bt = Wt + 0 * 65536; C = PA0; M = ND; }
    else if (gi < 2 * NB_D)   { gi -= NB_D;            Xf = xd; Bt = Wt + 3 * 65536; C = RA3; M = ND; }
    else if (gi < 2 * NB_D + NB_S) { gi -= 2 * NB_D;   Xf = xs; Bt = Wt + 2 * 65536; C = PB2; M = NS; }
    else                      { gi -= 2 * NB_D + NB_S; Xf = xs; Bt = Wt + 1 * 65536; C = RB1; M = NS; }
    const int bm0 = (gi >> 1) * 128;
    const int n0b = (gi & 1) * 128;

    const int lane = t & 63, w = t >> 6;
    const int wr = w >> 1, wc = w & 1;
    const int fr = lane & 15, g = lane >> 4;
    const int r8 = lane >> 3, slotL = lane & 7;
    const int ar_ = t >> 1, ah = t & 1;       // A-stage: row, k-half
    int ra = bm0 + ar_; if (ra >= M) ra = M - 1;
    const int arm = ar_ & 7;

    f32x4 acc[4][4];
#pragma unroll
    for (int m = 0; m < 4; ++m)
#pragma unroll
        for (int n = 0; n < 4; ++n)
            acc[m][n] = (f32x4){0.f, 0.f, 0.f, 0.f};

    for (int st = 0; st < 4; ++st) {
        const int k0 = st * 64;
#pragma unroll
        for (int j = 0; j < 4; ++j) {
            const int is = w * 4 + j;
            const int rowb = is * 8 + r8;
            const int sl = slotL ^ (rowb & 7);
            gload_lds16(Bt + (size_t)(n0b + rowb) * 256 + k0 + sl * 8, &Bs[is * 512]);
        }
        {
            const float* arow = Xf + (size_t)ra * 256 + k0 + ah * 32;
            unsigned short* awr = &As[ar_ * 64];
#pragma unroll
            for (int q2 = 0; q2 < 4; ++q2) {
                const int q = ah * 4 + q2;
                float4 f0 = *reinterpret_cast<const float4*>(arow + q2 * 8);
                float4 f1 = *reinterpret_cast<const float4*>(arow + q2 * 8 + 4);
                short8 v;
                v[0] = (short)f2b(f0.x); v[1] = (short)f2b(f0.y);
                v[2] = (short)f2b(f0.z); v[3] = (short)f2b(f0.w);
                v[4] = (short)f2b(f1.x); v[5] = (short)f2b(f1.y);
                v[6] = (short)f2b(f1.z); v[7] = (short)f2b(f1.w);
                *reinterpret_cast<short8*>(awr + (q ^ arm) * 8) = v;
            }
        }
        __syncthreads();
#pragma unroll
        for (int kc = 0; kc < 2; ++kc) {
            const int q = kc * 4 + g;
            short8 a[4], bb[4];
#pragma unroll
            for (int n = 0; n < 4; ++n) {
                const int br = wc * 64 + n * 16 + fr;
                bb[n] = *reinterpret_cast<const short8*>(&Bs[br * 64 + (q ^ (fr & 7)) * 8]);
            }
#pragma unroll
            for (int m = 0; m < 4; ++m) {
                const int arr = wr * 64 + m * 16 + fr;
                a[m] = *reinterpret_cast<const short8*>(&As[arr * 64 + (q ^ (fr & 7)) * 8]);
            }
#pragma unroll
            for (int m = 0; m < 4; ++m)
#pragma unroll
                for (int n = 0; n < 4; ++n)
                    acc[m][n] = __builtin_amdgcn_mfma_f32_16x16x32_bf16(a[m], bb[n], acc[m][n], 0, 0, 0);
        }
        __syncthreads();
    }

#pragma unroll
    for (int n = 0; n < 4; ++n) {
        const int col = n0b + wc * 64 + n * 16 + fr;
#pragma unroll
        for (int m = 0; m < 4; ++m) {
#pragma unroll
            for (int r = 0; r < 4; ++r) {
                int row = bm0 + wr * 64 + m * 16 + g * 4 + r;
                if (row < M) C[row * 256 + col] = f2b(acc[m][n][r]);
            }
        }
    }
}

// ---------------- fused mean aggregation of PROJECTED rows + direct term + bias ----------------

__global__ __launch_bounds__(256) void agg_fused(const unsigned short* __restrict__ gatherDrug,
                                                 const unsigned short* __restrict__ gatherDis,
                                                 const int* __restrict__ row_dis,
                                                 const int* __restrict__ row_drug,
                                                 const unsigned short* __restrict__ val_ds,
                                                 const unsigned short* __restrict__ val_sd,
                                                 const float* __restrict__ inv_dis,
                                                 const float* __restrict__ inv_drug,
                                                 const unsigned short* __restrict__ dirDis,
                                                 const unsigned short* __restrict__ dirDrug,
                                                 const float* __restrict__ bDis,
                                                 const float* __restrict__ bDrug,
                                                 unsigned short* __restrict__ outDis,
                                                 unsigned short* __restrict__ outDrug,
                                                 int do_relu) {
    int wid = threadIdx.x >> 6, lane = threadIdx.x & 63;
    int node = blockIdx.x * 4 + wid;
    const int half = lane >> 5;
    const int sub = lane & 31;
    const unsigned short* xsrc; const int* row; const unsigned short* vals;
    const float* inv; const unsigned short* dirp; const float* bias; unsigned short* outp;
    if (node < NS) {
        xsrc = gatherDrug; row = row_dis; vals = val_ds; inv = inv_dis;
        dirp = dirDis; bias = bDis; outp = outDis;
    } else {
        node -= NS;
        if (node >= ND) return;
        xsrc = gatherDis; row = row_drug; vals = val_sd; inv = inv_drug;
        dirp = dirDrug; bias = bDrug; outp = outDrug;
    }
    const int beg = row[node], end = row[node + 1];
    const int off = sub * 8;
    float a[8] = {};
    int j = beg;
    for (; j + 8 <= end; j += 8) {
        int r0 = vals[j     + half];
        int r1 = vals[j + 2 + half];
        int r2 = vals[j + 4 + half];
        int r3 = vals[j + 6 + half];
        short8 v0 = *reinterpret_cast<const short8*>(xsrc + r0 * 256 + off);
        short8 v1 = *reinterpret_cast<const short8*>(xsrc + r1 * 256 + off);
        short8 v2 = *reinterpret_cast<const short8*>(xsrc + r2 * 256 + off);
        short8 v3 = *reinterpret_cast<const short8*>(xsrc + r3 * 256 + off);
#pragma unroll
        for (int k = 0; k < 8; ++k)
            a[k] += b2f((unsigned short)v0[k]) + b2f((unsigned short)v1[k])
                  + b2f((unsigned short)v2[k]) + b2f((unsigned short)v3[k]);
    }
    for (; j + 2 <= end; j += 2) {
        int r = vals[j + half];
        short8 v = *reinterpret_cast<const short8*>(xsrc + r * 256 + off);
#pragma unroll
        for (int k = 0; k < 8; ++k) a[k] += b2f((unsigned short)v[k]);
    }
    if (j < end && half == 0) {
        int r = vals[j];
        short8 v = *reinterpret_cast<const short8*>(xsrc + r * 256 + off);
#pragma unroll
        for (int k = 0; k < 8; ++k) a[k] += b2f((unsigned short)v[k]);
    }
#pragma unroll
    for (int k = 0; k < 8; ++k) a[k] += __shfl_xor(a[k], 32);
    if (half == 0) {
        const float iv = inv[node];
        short8 dir = *reinterpret_cast<const short8*>(dirp + node * 256 + off);
        float4 b0 = *reinterpret_cast<const float4*>(bias + off);
        float4 b1 = *reinterpret_cast<const float4*>(bias + off + 4);
        float bb[8] = { b0.x, b0.y, b0.z, b0.w, b1.x, b1.y, b1.z, b1.w };
        short8 o;
#pragma unroll
        for (int k = 0; k < 8; ++k) {
            float v = a[k] * iv + b2f((unsigned short)dir[k]) + bb[k];
            if (do_relu) v = fmaxf(v, 0.f);
            o[k] = (short)f2b(v);
        }
        *reinterpret_cast<short8*>(outp + node * 256 + off) = o;
    }
}

// ---------------- LDS-staged bf16 GEMM, 4 single-product segments ----------------

struct Seg1 {
    const unsigned short* A;
    const unsigned short* Bt;
    unsigned short* C;
    int M; int nblk;
};

__global__ __launch_bounds__(256) void gemm_lds4(Seg1 s0, Seg1 s1, Seg1 s2, Seg1 s3) {
    __shared__ unsigned short As[128 * 64];
    __shared__ unsigned short Bs[128 * 64];
    Seg1 s;
    int bx = blockIdx.x;
    if (bx < s0.nblk) s = s0;
    else if (bx < s0.nblk + s1.nblk) { s = s1; bx -= s0.nblk; }
    else if (bx < s0.nblk + s1.nblk + s2.nblk) { s = s2; bx -= s0.nblk + s1.nblk; }
    else { s = s3; bx -= s0.nblk + s1.nblk + s2.nblk; }

    const int t = threadIdx.x;
    const int lane = t & 63, w = t >> 6;
    const int wr = w >> 1, wc = w & 1;
    const int fr = lane & 15, g = lane >> 4;
    const int bm0 = bx * 128;
    const int n0b = (int)blockIdx.y * 128;
    const int M = s.M;
    const int r8 = lane >> 3, slotL = lane & 7;

    f32x4 acc[4][4];
#pragma unroll
    for (int m = 0; m < 4; ++m)
#pragma unroll
        for (int n = 0; n < 4; ++n)
            acc[m][n] = (f32x4){0.f, 0.f, 0.f, 0.f};

    for (int st = 0; st < 4; ++st) {
        const int k0 = st * 64;
#pragma unroll
        for (int j = 0; j < 4; ++j) {
            const int is = w * 4 + j;
            const int row = is * 8 + r8;
            const int sl = slotL ^ (row & 7);
            int ra = bm0 + row; if (ra >= M) ra = M - 1;
            gload_lds16(s.A + (size_t)ra * 256 + k0 + sl * 8, &As[is * 512]);
            gload_lds16(s.Bt + (size_t)(n0b + row) * 256 + k0 + sl * 8, &Bs[is * 512]);
        }
        __syncthreads();
#pragma unroll
        for (int kc = 0; kc < 2; ++kc) {
            const int q = kc * 4 + g;
            short8 a[4], b[4];
#pragma unroll
            for (int n = 0; n < 4; ++n) {
                const int br = wc * 64 + n * 16 + fr;
                b[n] = *reinterpret_cast<const short8*>(&Bs[br * 64 + (q ^ (fr & 7)) * 8]);
            }
#pragma unroll
            for (int m = 0; m < 4; ++m) {
                const int ar = wr * 64 + m * 16 + fr;
                a[m] = *reinterpret_cast<const short8*>(&As[ar * 64 + (q ^ (fr & 7)) * 8]);
            }
#pragma unroll
            for (int m = 0; m < 4; ++m)
#pragma unroll
                for (int n = 0; n < 4; ++n)
                    acc[m][n] = __builtin_amdgcn_mfma_f32_16x16x32_bf16(a[m], b[n], acc[m][n], 0, 0, 0);
        }
        __syncthreads();
    }

#pragma unroll
    for (int n = 0; n < 4; ++n) {
        const int col = n0b + wc * 64 + n * 16 + fr;
#pragma unroll
        for (int m = 0; m < 4; ++m) {
#pragma unroll
            for (int r = 0; r < 4; ++r) {
                int row = bm0 + wr * 64 + m * 16 + g * 4 + r;
                if (row < M) s.C[row * 256 + col] = f2b(acc[m][n][r]);
            }
        }
    }
}

// ---------------- edge decoder ----------------

__global__ __launch_bounds__(256) void dec_edge(const unsigned short* __restrict__ Pd,
                                                const unsigned short* __restrict__ Ps,
                                                const int* __restrict__ lrow,
                                                const int* __restrict__ lcol,
                                                const float* __restrict__ b1,
                                                const float* __restrict__ w2,
                                                const float* __restrict__ b2,
                                                float* __restrict__ outp, int n) {
    int wid = threadIdx.x >> 6, lane = threadIdx.x & 63;
    int half = lane >> 5, sl = lane & 31;
    int e = blockIdx.x * 8 + wid * 2 + half;
    if (e >= n) return;
    int r = lrow[e], c = lcol[e];
    const int off = sl * 8;
    short8 pd = *reinterpret_cast<const short8*>(Pd + r * 256 + off);
    short8 ps = *reinterpret_cast<const short8*>(Ps + c * 256 + off);
    float s = 0.f;
#pragma unroll
    for (int k = 0; k < 8; ++k) {
        float h = b2f((unsigned short)pd[k]) + b2f((unsigned short)ps[k]) + b1[off + k];
        s += fmaxf(h, 0.f) * w2[off + k];
    }
#pragma unroll
    for (int o = 16; o; o >>= 1) s += __shfl_down(s, o, 32);
    if (sl == 0) outp[e] = s + b2[0];
}

// ---------------- launch ----------------

extern "C" void kernel_launch(void* const* d_in, const int* in_sizes, int n_in,
                              void* d_out, int out_size, void* d_ws, size_t ws_size,
                              hipStream_t stream) {
    const float* x_drug = (const float*)d_in[0];
    const float* x_dis  = (const float*)d_in[1];
    const int* esrc = (const int*)d_in[2];
    const int* edst = (const int*)d_in[3];
    const int* lrow = (const int*)d_in[4];
    const int* lcol = (const int*)d_in[5];
    const float* Wl1_ds = (const float*)d_in[6];
    const float* bl1_ds = (const float*)d_in[7];
    const float* Wr1_ds = (const float*)d_in[8];
    const float* Wl1_sd = (const float*)d_in[9];
    const float* bl1_sd = (const float*)d_in[10];
    const float* Wr1_sd = (const float*)d_in[11];
    const float* Wl2_ds = (const float*)d_in[12];
    const float* bl2_ds = (const float*)d_in[13];
    const float* Wr2_ds = (const float*)d_in[14];
    const float* Wl2_sd = (const float*)d_in[15];
    const float* bl2_sd = (const float*)d_in[16];
    const float* Wr2_sd = (const float*)d_in[17];
    const float* Wdec1 = (const float*)d_in[18];
    const float* bdec1 = (const float*)d_in[19];
    const float* Wdec2 = (const float*)d_in[20];
    const float* bdec2 = (const float*)d_in[21];
    float* outp = (float*)d_out;

    char* ws = (char*)d_ws;
    size_t off = 0;
    auto alloc = [&](size_t bytes) -> void* {
        void* p = ws + off;
        off = (off + bytes + 255) & ~(size_t)255;
        return p;
    };
    int* cnt       = (int*)alloc((size_t)NTOT * 4);
    int* bsum      = (int*)alloc((size_t)SCAN_BLK * 4);
    int* row_dis   = (int*)alloc((size_t)(NS + 1) * 4);
    int* row_drug  = (int*)alloc((size_t)(ND + 1) * 4);
    float* inv_dis = (float*)alloc((size_t)NS * 4);
    float* inv_drug= (float*)alloc((size_t)ND * 4);
    float* cbuf    = (float*)alloc((size_t)512 * 4);
    unsigned short* rank_ds = (unsigned short*)alloc((size_t)NE * 2);
    unsigned short* rank_sd = (unsigned short*)alloc((size_t)NE * 2);
    unsigned short* val_ds  = (unsigned short*)alloc((size_t)NE * 2);
    unsigned short* val_sd  = (unsigned short*)alloc((size_t)NE * 2);
    unsigned short* Wt   = (unsigned short*)alloc((size_t)8 * 65536 * 2);
    unsigned short* PA0  = (unsigned short*)alloc((size_t)ND * 256 * 2);  // Xd@Wl1_ds -> G1 reuse
    unsigned short* RA3  = (unsigned short*)alloc((size_t)ND * 256 * 2);  // Xd@Wr1_sd -> G4 reuse
    unsigned short* PB2  = (unsigned short*)alloc((size_t)NS * 256 * 2);  // Xs@Wl1_sd -> G2 reuse
    unsigned short* RB1  = (unsigned short*)alloc((size_t)NS * 256 * 2);  // Xs@Wr1_ds -> G3 reuse
    unsigned short* zs1  = (unsigned short*)alloc((size_t)NS * 256 * 2);
    unsigned short* zd1  = (unsigned short*)alloc((size_t)ND * 256 * 2);
    unsigned short* Ps   = (unsigned short*)alloc((size_t)NS * 256 * 2);
    unsigned short* Pd   = (unsigned short*)alloc((size_t)ND * 256 * 2);
    int* cnt_dis = cnt;
    int* cnt_drug = cnt + NS;

    // --- zero counters (graph-capturable memset) ---
    hipMemsetAsync(cnt, 0, (size_t)NTOT * 4, stream);

    // --- rank atomics || W prep (transpose + decoder-fold compose) ---
    WAll wa;
    wa.w1[0] = Wl1_ds; wa.w1[1] = Wr1_ds; wa.w1[2] = Wl1_sd; wa.w1[3] = Wr1_sd;
    wa.w2[0] = Wl2_ds; wa.w2[1] = Wr2_ds; wa.w2[2] = Wl2_sd; wa.w2[3] = Wr2_sd;
    wa.wdec1 = Wdec1; wa.bl2_ds = bl2_ds; wa.bl2_sd = bl2_sd;
    rank_w<<<RW_BLKS, 256, 0, stream>>>(esrc, edst, cnt_drug, cnt_dis,
                                        rank_sd, rank_ds, wa, Wt, cbuf);

    // --- scan ---
    scan_part<<<SCAN_BLK, 256, 0, stream>>>(cnt, bsum);
    scan_top<<<1, 64, 0, stream>>>(bsum, SCAN_BLK);
    scan_emit<<<SCAN_BLK, 256, 0, stream>>>(cnt, bsum, row_dis, row_drug, inv_dis, inv_drug);

    // --- place scatter || layer-1 GEMMs (S.(X@W) factorization) ---
    place_gemm<<<PG_BLKS, 256, 0, stream>>>(esrc, edst, row_drug, row_dis,
                                            rank_sd, rank_ds, val_sd, val_ds,
                                            x_drug, x_dis, Wt, PA0, RA3, PB2, RB1);

    const int AGG_GRID = (NTOT + 3) / 4;

    // --- layer 1: zs1 = relu(agg(PA0) + RB1 + b), zd1 = relu(agg(PB2) + RA3 + b) ---
    agg_fused<<<AGG_GRID, 256, 0, stream>>>(PA0, PB2, row_dis, row_drug, val_ds, val_sd,
                                            inv_dis, inv_drug, RB1, RA3, bl1_ds, bl1_sd,
                                            zs1, zd1, 1);

    // --- layer 2 + decoder fold GEMMs ---
    unsigned short* G1 = PA0;
    unsigned short* G4 = RA3;
    unsigned short* G2 = PB2;
    unsigned short* G3 = RB1;
    {
        Seg1 a = { zd1, Wt + (size_t)4 * 65536, G1, ND, 391 };
        Seg1 b = { zs1, Wt + (size_t)5 * 65536, G2, NS, 235 };
        Seg1 c = { zs1, Wt + (size_t)6 * 65536, G3, NS, 235 };
        Seg1 d = { zd1, Wt + (size_t)7 * 65536, G4, ND, 391 };
        dim3 grid(391 + 235 + 235 + 391, 2);
        gemm_lds4<<<grid, 256, 0, stream>>>(a, b, c, d);
    }

    // --- Ps = agg(G1) + G2 + cb_s ; Pd = agg(G3) + G4 + cb_d ---
    agg_fused<<<AGG_GRID, 256, 0, stream>>>(G1, G3, row_dis, row_drug, val_ds, val_sd,
                                            inv_dis, inv_drug, G2, G4, cbuf, cbuf + 256,
                                            Ps, Pd, 0);

    // --- edge decoder ---
    dec_edge<<<(EL + 7) / 8, 256, 0, stream>>>(Pd, Ps, lrow, lcol, bdec1, Wdec2, bdec2, outp, EL);
}

// Round 16
// 524.624 us; speedup vs baseline: 1.0982x; 1.0982x over previous
//
#include <hip/hip_runtime.h>
#include <hip/hip_bf16.h>

#define ND 50000
#define NS 30000
#define NE 1000000
#define EL 200000
#define NTOT (NS + ND)          // 80000
#define SCAN_BLK ((NTOT + 1023) / 1024)   // 79

#define ZERO_BLKS ((NTOT + 255) / 256)    // 313
#define TRW4_BLKS 1024                    // 4 mats * 65536 / 256
#define COMP_BLKS 64
#define BIAS_BLKS 2
#define WPREP_BLKS (ZERO_BLKS + TRW4_BLKS + COMP_BLKS + BIAS_BLKS)

#define RANK_BLKS ((NE + 255) / 256)      // 3907
#define NB_D (391 * 2)                    // 782
#define NB_S (235 * 2)                    // 470
#define GEMM1_BLKS (2 * NB_D + 2 * NB_S)  // 2504
#define MEGA_GRP 1252                     // full 3:2 groups
#define MEGA_BLKS (RANK_BLKS + GEMM1_BLKS)  // 6411

typedef short short8 __attribute__((ext_vector_type(8)));
typedef float f32x4 __attribute__((ext_vector_type(4)));

__device__ __forceinline__ float b2f(unsigned short u) {
    union { unsigned int i; float f; } c; c.i = ((unsigned int)u) << 16; return c.f;
}
__device__ __forceinline__ unsigned short f2b(float f) {
    __hip_bfloat16 h = __float2bfloat16(f);   // RNE
    union { __hip_bfloat16 h; unsigned short u; } c; c.h = h; return c.u;
}

__device__ __forceinline__ void gload_lds16(const unsigned short* g, unsigned short* l) {
    __builtin_amdgcn_global_load_lds(
        (const __attribute__((address_space(1))) unsigned int*)g,
        (__attribute__((address_space(3))) unsigned int*)l, 16, 0, 0);
}

struct WAll {
    const float* w1[4];      // Wl1_ds, Wr1_ds, Wl1_sd, Wr1_sd  -> WT[0..3]
    const float* w2[4];      // Wl2_ds, Wr2_ds, Wl2_sd, Wr2_sd  -> WT[4..7] composed
    const float* wdec1;
    const float* bl2_ds;
    const float* bl2_sd;
};

// ---------------- wprep: zero counters + transpose W1 + compose W2@Wdec ----------------

__global__ __launch_bounds__(256) void wprep(int* __restrict__ cnt, WAll wa,
                                             unsigned short* __restrict__ Wt,
                                             float* __restrict__ cbuf) {
    int b = blockIdx.x, t = threadIdx.x;
    if (b < ZERO_BLKS) {
        int i = b * 256 + t;
        if (i < NTOT) cnt[i] = 0;
    } else if (b < ZERO_BLKS + TRW4_BLKS) {
        int o = (b - ZERO_BLKS) * 256 + t;
        int mat = o >> 16, i2 = o & 65535;
        int n = i2 >> 8, k = i2 & 255;
        Wt[o] = f2b(wa.w1[mat][k * 256 + n]);
    } else if (b < ZERO_BLKS + TRW4_BLKS + COMP_BLKS) {
        int idx = b - ZERO_BLKS - TRW4_BLKS;
        int mat = idx >> 4;
        int k0 = (idx & 15) * 16;
        const float* W2 = wa.w2[mat];
        const float* Wd = wa.wdec1 + ((mat < 2) ? 65536 : 0);
        float acc[16] = {};
        const int n = t;
        for (int j = 0; j < 256; ++j) {
            float wd = Wd[j * 256 + n];
#pragma unroll
            for (int k = 0; k < 16; ++k) acc[k] += W2[(k0 + k) * 256 + j] * wd;
        }
        unsigned short* dst = Wt + (size_t)(4 + mat) * 65536 + n * 256 + k0;
#pragma unroll
        for (int k = 0; k < 16; ++k) dst[k] = f2b(acc[k]);
    } else {
        int idx = b - ZERO_BLKS - TRW4_BLKS - COMP_BLKS;
        const float* bsrc = idx ? wa.bl2_sd : wa.bl2_ds;
        const float* Wd = wa.wdec1 + (idx ? 0 : 65536);
        float acc = 0.f;
        const int n = t;
        for (int j = 0; j < 256; ++j) acc += bsrc[j] * Wd[j * 256 + n];
        cbuf[idx * 256 + n] = acc;
    }
}

// ---------------- mega: rank atomics (latency-bound, ~125us floor) || layer-1 GEMMs ----------------
// (S.X)@W = S.(X@W): the 4 layer-1 products need no CSR -> co-run under the rank shadow.
__global__ __launch_bounds__(256) void mega(const int* __restrict__ esrc,
                                            const int* __restrict__ edst,
                                            int* cnt_drug, int* cnt_dis,
                                            unsigned short* __restrict__ rank_sd,
                                            unsigned short* __restrict__ rank_ds,
                                            const float* __restrict__ xd,
                                            const float* __restrict__ xs,
                                            const unsigned short* __restrict__ Wt,
                                            unsigned short* __restrict__ PA0,
                                            unsigned short* __restrict__ RA3,
                                            unsigned short* __restrict__ PB2,
                                            unsigned short* __restrict__ RB1) {
    __shared__ unsigned short As[128 * 64];
    __shared__ unsigned short Bs[128 * 64];
    const int b = blockIdx.x, t = threadIdx.x;
    int role, idx;
    if (b < 5 * MEGA_GRP) {
        int g = b / 5, r = b - g * 5;
        if (r < 3) { role = 0; idx = g * 3 + r; }
        else       { role = 1; idx = g * 2 + r - 3; }
    } else {
        role = 0; idx = 3 * MEGA_GRP + (b - 5 * MEGA_GRP);
    }

    if (role == 0) {
        int i = idx * 256 + t;
        if (i < NE) {
            int s = esrc[i], d = edst[i];
            rank_ds[i] = (unsigned short)atomicAdd(&cnt_dis[d], 1);
            rank_sd[i] = (unsigned short)atomicAdd(&cnt_drug[s], 1);
        }
        return;
    }

    // ---- gemm role: 4 single-product segments ----
    int gi = idx;
    const float* Xf; const unsigned short* Bt; unsigned short* C; int M;
    if (gi < NB_D)            { Xf = xd; Bt = Wt + 0 * 65536; C = PA0; M = ND; }
    else if (gi < 2 * NB_D)   { gi -= NB_D;            Xf = xd; Bt = Wt + 3 * 65536; C = RA3; M = ND; }
    else if (gi < 2 * NB_D + NB_S) { gi -= 2 * NB_D;   Xf = xs; Bt = Wt + 2 * 65536; C = PB2; M = NS; }
    else                      { gi -= 2 * NB_D + NB_S; Xf = xs; Bt = Wt + 1 * 65536; C = RB1; M = NS; }
    const int bm0 = (gi >> 1) * 128;
    const int n0b = (gi & 1) * 128;

    const int lane = t & 63, w = t >> 6;
    const int wr = w >> 1, wc = w & 1;
    const int fr = lane & 15, g = lane >> 4;
    const int r8 = lane >> 3, slotL = lane & 7;
    const int ar_ = t >> 1, ah = t & 1;       // A-stage: row, k-half
    int ra = bm0 + ar_; if (ra >= M) ra = M - 1;
    const int arm = ar_ & 7;

    f32x4 acc[4][4];
#pragma unroll
    for (int m = 0; m < 4; ++m)
#pragma unroll
        for (int n = 0; n < 4; ++n)
            acc[m][n] = (f32x4){0.f, 0.f, 0.f, 0.f};

    for (int st = 0; st < 4; ++st) {
        const int k0 = st * 64;
        // B: async global->LDS (linear dest, source pre-swizzled)
#pragma unroll
        for (int j = 0; j < 4; ++j) {
            const int is = w * 4 + j;
            const int rowb = is * 8 + r8;
            const int sl = slotL ^ (rowb & 7);
            gload_lds16(Bt + (size_t)(n0b + rowb) * 256 + k0 + sl * 8, &Bs[is * 512]);
        }
        // A: fp32 -> bf16 reg-stage, swizzled ds_write
        {
            const float* arow = Xf + (size_t)ra * 256 + k0 + ah * 32;
            unsigned short* awr = &As[ar_ * 64];
#pragma unroll
            for (int q2 = 0; q2 < 4; ++q2) {
                const int q = ah * 4 + q2;
                float4 f0 = *reinterpret_cast<const float4*>(arow + q2 * 8);
                float4 f1 = *reinterpret_cast<const float4*>(arow + q2 * 8 + 4);
                short8 v;
                v[0] = (short)f2b(f0.x); v[1] = (short)f2b(f0.y);
                v[2] = (short)f2b(f0.z); v[3] = (short)f2b(f0.w);
                v[4] = (short)f2b(f1.x); v[5] = (short)f2b(f1.y);
                v[6] = (short)f2b(f1.z); v[7] = (short)f2b(f1.w);
                *reinterpret_cast<short8*>(awr + (q ^ arm) * 8) = v;
            }
        }
        __syncthreads();
#pragma unroll
        for (int kc = 0; kc < 2; ++kc) {
            const int q = kc * 4 + g;
            short8 a[4], bb[4];
#pragma unroll
            for (int n = 0; n < 4; ++n) {
                const int br = wc * 64 + n * 16 + fr;
                bb[n] = *reinterpret_cast<const short8*>(&Bs[br * 64 + (q ^ (fr & 7)) * 8]);
            }
#pragma unroll
            for (int m = 0; m < 4; ++m) {
                const int arr = wr * 64 + m * 16 + fr;
                a[m] = *reinterpret_cast<const short8*>(&As[arr * 64 + (q ^ (fr & 7)) * 8]);
            }
#pragma unroll
            for (int m = 0; m < 4; ++m)
#pragma unroll
                for (int n = 0; n < 4; ++n)
                    acc[m][n] = __builtin_amdgcn_mfma_f32_16x16x32_bf16(a[m], bb[n], acc[m][n], 0, 0, 0);
        }
        __syncthreads();
    }

#pragma unroll
    for (int n = 0; n < 4; ++n) {
        const int col = n0b + wc * 64 + n * 16 + fr;
#pragma unroll
        for (int m = 0; m < 4; ++m) {
#pragma unroll
            for (int r = 0; r < 4; ++r) {
                int row = bm0 + wr * 64 + m * 16 + g * 4 + r;
                if (row < M) C[row * 256 + col] = f2b(acc[m][n][r]);
            }
        }
    }
}

// ---------------- scan ----------------

__global__ __launch_bounds__(256) void scan_part(const int* __restrict__ cnt,
                                                 int* __restrict__ bsum) {
    __shared__ int red[4];
    int t = threadIdx.x, lane = t & 63, wid = t >> 6;
    int base = blockIdx.x * 1024 + t * 4;
    int s = 0;
    if (base < NTOT) {
        int4 c = *reinterpret_cast<const int4*>(cnt + base);
        s = c.x + c.y + c.z + c.w;
    }
#pragma unroll
    for (int off = 32; off; off >>= 1) s += __shfl_down(s, off);
    if (lane == 0) red[wid] = s;
    __syncthreads();
    if (t == 0) bsum[blockIdx.x] = red[0] + red[1] + red[2] + red[3];
}

__global__ void scan_top(int* bsum, int nb) {
    int lane = threadIdx.x;
    int a0 = lane < nb ? bsum[lane] : 0;
    int a1 = (64 + lane) < nb ? bsum[64 + lane] : 0;
    int i0 = a0, i1 = a1;
#pragma unroll
    for (int off = 1; off < 64; off <<= 1) {
        int t0 = __shfl_up(i0, off);
        int t1 = __shfl_up(i1, off);
        if (lane >= off) { i0 += t0; i1 += t1; }
    }
    int tot0 = __shfl(i0, 63);
    if (lane < nb) bsum[lane] = i0 - a0;
    if (64 + lane < nb) bsum[64 + lane] = tot0 + i1 - a1;
}

__global__ __launch_bounds__(256) void scan_emit(const int* __restrict__ cnt,
                                                 const int* __restrict__ boff,
                                                 int* __restrict__ row_dis,
                                                 int* __restrict__ row_drug,
                                                 float* __restrict__ inv_dis,
                                                 float* __restrict__ inv_drug) {
    __shared__ int wsum[4];
    int t = threadIdx.x, lane = t & 63, wid = t >> 6;
    int base = blockIdx.x * 1024 + t * 4;
    int4 c = make_int4(0, 0, 0, 0);
    if (base < NTOT) c = *reinterpret_cast<const int4*>(cnt + base);
    int sl = c.x + c.y + c.z + c.w;
    int sc = sl;
#pragma unroll
    for (int off = 1; off < 64; off <<= 1) {
        int tv = __shfl_up(sc, off);
        if (lane >= off) sc += tv;
    }
    if (lane == 63) wsum[wid] = sc;
    __syncthreads();
    int woff = 0;
    for (int w2 = 0; w2 < wid; ++w2) woff += wsum[w2];
    int run = boff[blockIdx.x] + woff + (sc - sl);
    int cc[4] = { c.x, c.y, c.z, c.w };
    if (base < NTOT) {
#pragma unroll
        for (int k = 0; k < 4; ++k) {
            int i = base + k;
            float iv = 1.0f / (float)(cc[k] > 1 ? cc[k] : 1);
            if (i < NS) { row_dis[i] = run; inv_dis[i] = iv; }
            else        { row_drug[i - NS] = run - NE; inv_drug[i - NS] = iv; }
            run += cc[k];
        }
    }
    if (blockIdx.x == 0 && t == 0) { row_dis[NS] = NE; row_drug[ND] = NE; }
}

__global__ void place_kernel(const int* __restrict__ src, const int* __restrict__ dst,
                             const int* __restrict__ row_drug, const int* __restrict__ row_dis,
                             const unsigned short* __restrict__ rank_sd,
                             const unsigned short* __restrict__ rank_ds,
                             unsigned short* __restrict__ val_sd,
                             unsigned short* __restrict__ val_ds, int n) {
    int i = blockIdx.x * blockDim.x + threadIdx.x;
    if (i < n) {
        int s = src[i], d = dst[i];
        val_ds[row_dis[d] + (int)rank_ds[i]] = (unsigned short)s;
        val_sd[row_drug[s] + (int)rank_sd[i]] = (unsigned short)d;
    }
}

// ---------------- fused mean aggregation of PROJECTED rows + direct term + bias ----------------

__global__ __launch_bounds__(256) void agg_fused(const unsigned short* __restrict__ gatherDrug,
                                                 const unsigned short* __restrict__ gatherDis,
                                                 const int* __restrict__ row_dis,
                                                 const int* __restrict__ row_drug,
                                                 const unsigned short* __restrict__ val_ds,
                                                 const unsigned short* __restrict__ val_sd,
                                                 const float* __restrict__ inv_dis,
                                                 const float* __restrict__ inv_drug,
                                                 const unsigned short* __restrict__ dirDis,
                                                 const unsigned short* __restrict__ dirDrug,
                                                 const float* __restrict__ bDis,
                                                 const float* __restrict__ bDrug,
                                                 unsigned short* __restrict__ outDis,
                                                 unsigned short* __restrict__ outDrug,
                                                 int do_relu) {
    int wid = threadIdx.x >> 6, lane = threadIdx.x & 63;
    int node = blockIdx.x * 4 + wid;
    const int half = lane >> 5;
    const int sub = lane & 31;
    const unsigned short* xsrc; const int* row; const unsigned short* vals;
    const float* inv; const unsigned short* dirp; const float* bias; unsigned short* outp;
    if (node < NS) {
        xsrc = gatherDrug; row = row_dis; vals = val_ds; inv = inv_dis;
        dirp = dirDis; bias = bDis; outp = outDis;
    } else {
        node -= NS;
        if (node >= ND) return;
        xsrc = gatherDis; row = row_drug; vals = val_sd; inv = inv_drug;
        dirp = dirDrug; bias = bDrug; outp = outDrug;
    }
    const int beg = row[node], end = row[node + 1];
    const int off = sub * 8;
    float a[8] = {};
    int j = beg;
    for (; j + 8 <= end; j += 8) {
        int r0 = vals[j     + half];
        int r1 = vals[j + 2 + half];
        int r2 = vals[j + 4 + half];
        int r3 = vals[j + 6 + half];
        short8 v0 = *reinterpret_cast<const short8*>(xsrc + r0 * 256 + off);
        short8 v1 = *reinterpret_cast<const short8*>(xsrc + r1 * 256 + off);
        short8 v2 = *reinterpret_cast<const short8*>(xsrc + r2 * 256 + off);
        short8 v3 = *reinterpret_cast<const short8*>(xsrc + r3 * 256 + off);
#pragma unroll
        for (int k = 0; k < 8; ++k)
            a[k] += b2f((unsigned short)v0[k]) + b2f((unsigned short)v1[k])
                  + b2f((unsigned short)v2[k]) + b2f((unsigned short)v3[k]);
    }
    for (; j + 2 <= end; j += 2) {
        int r = vals[j + half];
        short8 v = *reinterpret_cast<const short8*>(xsrc + r * 256 + off);
#pragma unroll
        for (int k = 0; k < 8; ++k) a[k] += b2f((unsigned short)v[k]);
    }
    if (j < end && half == 0) {
        int r = vals[j];
        short8 v = *reinterpret_cast<const short8*>(xsrc + r * 256 + off);
#pragma unroll
        for (int k = 0; k < 8; ++k) a[k] += b2f((unsigned short)v[k]);
    }
#pragma unroll
    for (int k = 0; k < 8; ++k) a[k] += __shfl_xor(a[k], 32);
    if (half == 0) {
        const float iv = inv[node];
        short8 dir = *reinterpret_cast<const short8*>(dirp + node * 256 + off);
        float4 b0 = *reinterpret_cast<const float4*>(bias + off);
        float4 b1 = *reinterpret_cast<const float4*>(bias + off + 4);
        float bb[8] = { b0.x, b0.y, b0.z, b0.w, b1.x, b1.y, b1.z, b1.w };
        short8 o;
#pragma unroll
        for (int k = 0; k < 8; ++k) {
            float v = a[k] * iv + b2f((unsigned short)dir[k]) + bb[k];
            if (do_relu) v = fmaxf(v, 0.f);
            o[k] = (short)f2b(v);
        }
        *reinterpret_cast<short8*>(outp + node * 256 + off) = o;
    }
}

// ---------------- LDS-staged bf16 GEMM, 4 single-product segments ----------------

struct Seg1 {
    const unsigned short* A;
    const unsigned short* Bt;
    unsigned short* C;
    int M; int nblk;
};

__global__ __launch_bounds__(256) void gemm_lds4(Seg1 s0, Seg1 s1, Seg1 s2, Seg1 s3) {
    __shared__ unsigned short As[128 * 64];
    __shared__ unsigned short Bs[128 * 64];
    Seg1 s;
    int bx = blockIdx.x;
    if (bx < s0.nblk) s = s0;
    else if (bx < s0.nblk + s1.nblk) { s = s1; bx -= s0.nblk; }
    else if (bx < s0.nblk + s1.nblk + s2.nblk) { s = s2; bx -= s0.nblk + s1.nblk; }
    else { s = s3; bx -= s0.nblk + s1.nblk + s2.nblk; }

    const int t = threadIdx.x;
    const int lane = t & 63, w = t >> 6;
    const int wr = w >> 1, wc = w & 1;
    const int fr = lane & 15, g = lane >> 4;
    const int bm0 = bx * 128;
    const int n0b = (int)blockIdx.y * 128;
    const int M = s.M;
    const int r8 = lane >> 3, slotL = lane & 7;

    f32x4 acc[4][4];
#pragma unroll
    for (int m = 0; m < 4; ++m)
#pragma unroll
        for (int n = 0; n < 4; ++n)
            acc[m][n] = (f32x4){0.f, 0.f, 0.f, 0.f};

    for (int st = 0; st < 4; ++st) {
        const int k0 = st * 64;
#pragma unroll
        for (int j = 0; j < 4; ++j) {
            const int is = w * 4 + j;
            const int row = is * 8 + r8;
            const int sl = slotL ^ (row & 7);
            int ra = bm0 + row; if (ra >= M) ra = M - 1;
            gload_lds16(s.A + (size_t)ra * 256 + k0 + sl * 8, &As[is * 512]);
            gload_lds16(s.Bt + (size_t)(n0b + row) * 256 + k0 + sl * 8, &Bs[is * 512]);
        }
        __syncthreads();
#pragma unroll
        for (int kc = 0; kc < 2; ++kc) {
            const int q = kc * 4 + g;
            short8 a[4], b[4];
#pragma unroll
            for (int n = 0; n < 4; ++n) {
                const int br = wc * 64 + n * 16 + fr;
                b[n] = *reinterpret_cast<const short8*>(&Bs[br * 64 + (q ^ (fr & 7)) * 8]);
            }
#pragma unroll
            for (int m = 0; m < 4; ++m) {
                const int ar = wr * 64 + m * 16 + fr;
                a[m] = *reinterpret_cast<const short8*>(&As[ar * 64 + (q ^ (fr & 7)) * 8]);
            }
#pragma unroll
            for (int m = 0; m < 4; ++m)
#pragma unroll
                for (int n = 0; n < 4; ++n)
                    acc[m][n] = __builtin_amdgcn_mfma_f32_16x16x32_bf16(a[m], b[n], acc[m][n], 0, 0, 0);
        }
        __syncthreads();
    }

#pragma unroll
    for (int n = 0; n < 4; ++n) {
        const int col = n0b + wc * 64 + n * 16 + fr;
#pragma unroll
        for (int m = 0; m < 4; ++m) {
#pragma unroll
            for (int r = 0; r < 4; ++r) {
                int row = bm0 + wr * 64 + m * 16 + g * 4 + r;
                if (row < M) s.C[row * 256 + col] = f2b(acc[m][n][r]);
            }
        }
    }
}

// ---------------- edge decoder ----------------

__global__ __launch_bounds__(256) void dec_edge(const unsigned short* __restrict__ Pd,
                                                const unsigned short* __restrict__ Ps,
                                                const int* __restrict__ lrow,
                                                const int* __restrict__ lcol,
                                                const float* __restrict__ b1,
                                                const float* __restrict__ w2,
                                                const float* __restrict__ b2,
                                                float* __restrict__ outp, int n) {
    int wid = threadIdx.x >> 6, lane = threadIdx.x & 63;
    int half = lane >> 5, sl = lane & 31;
    int e = blockIdx.x * 8 + wid * 2 + half;
    if (e >= n) return;
    int r = lrow[e], c = lcol[e];
    const int off = sl * 8;
    short8 pd = *reinterpret_cast<const short8*>(Pd + r * 256 + off);
    short8 ps = *reinterpret_cast<const short8*>(Ps + c * 256 + off);
    float s = 0.f;
#pragma unroll
    for (int k = 0; k < 8; ++k) {
        float h = b2f((unsigned short)pd[k]) + b2f((unsigned short)ps[k]) + b1[off + k];
        s += fmaxf(h, 0.f) * w2[off + k];
    }
#pragma unroll
    for (int o = 16; o; o >>= 1) s += __shfl_down(s, o, 32);
    if (sl == 0) outp[e] = s + b2[0];
}

// ---------------- launch ----------------

extern "C" void kernel_launch(void* const* d_in, const int* in_sizes, int n_in,
                              void* d_out, int out_size, void* d_ws, size_t ws_size,
                              hipStream_t stream) {
    const float* x_drug = (const float*)d_in[0];
    const float* x_dis  = (const float*)d_in[1];
    const int* esrc = (const int*)d_in[2];
    const int* edst = (const int*)d_in[3];
    const int* lrow = (const int*)d_in[4];
    const int* lcol = (const int*)d_in[5];
    const float* Wl1_ds = (const float*)d_in[6];
    const float* bl1_ds = (const float*)d_in[7];
    const float* Wr1_ds = (const float*)d_in[8];
    const float* Wl1_sd = (const float*)d_in[9];
    const float* bl1_sd = (const float*)d_in[10];
    const float* Wr1_sd = (const float*)d_in[11];
    const float* Wl2_ds = (const float*)d_in[12];
    const float* bl2_ds = (const float*)d_in[13];
    const float* Wr2_ds = (const float*)d_in[14];
    const float* Wl2_sd = (const float*)d_in[15];
    const float* bl2_sd = (const float*)d_in[16];
    const float* Wr2_sd = (const float*)d_in[17];
    const float* Wdec1 = (const float*)d_in[18];
    const float* bdec1 = (const float*)d_in[19];
    const float* Wdec2 = (const float*)d_in[20];
    const float* bdec2 = (const float*)d_in[21];
    float* outp = (float*)d_out;

    char* ws = (char*)d_ws;
    size_t off = 0;
    auto alloc = [&](size_t bytes) -> void* {
        void* p = ws + off;
        off = (off + bytes + 255) & ~(size_t)255;
        return p;
    };
    int* cnt       = (int*)alloc((size_t)NTOT * 4);
    int* bsum      = (int*)alloc((size_t)SCAN_BLK * 4);
    int* row_dis   = (int*)alloc((size_t)(NS + 1) * 4);
    int* row_drug  = (int*)alloc((size_t)(ND + 1) * 4);
    float* inv_dis = (float*)alloc((size_t)NS * 4);
    float* inv_drug= (float*)alloc((size_t)ND * 4);
    float* cbuf    = (float*)alloc((size_t)512 * 4);
    unsigned short* rank_ds = (unsigned short*)alloc((size_t)NE * 2);
    unsigned short* rank_sd = (unsigned short*)alloc((size_t)NE * 2);
    unsigned short* val_ds  = (unsigned short*)alloc((size_t)NE * 2);
    unsigned short* val_sd  = (unsigned short*)alloc((size_t)NE * 2);
    unsigned short* Wt   = (unsigned short*)alloc((size_t)8 * 65536 * 2);
    unsigned short* PA0  = (unsigned short*)alloc((size_t)ND * 256 * 2);  // Xd@Wl1_ds -> G1 reuse
    unsigned short* RA3  = (unsigned short*)alloc((size_t)ND * 256 * 2);  // Xd@Wr1_sd -> G4 reuse
    unsigned short* PB2  = (unsigned short*)alloc((size_t)NS * 256 * 2);  // Xs@Wl1_sd -> G2 reuse
    unsigned short* RB1  = (unsigned short*)alloc((size_t)NS * 256 * 2);  // Xs@Wr1_ds -> G3 reuse
    unsigned short* zs1  = (unsigned short*)alloc((size_t)NS * 256 * 2);
    unsigned short* zd1  = (unsigned short*)alloc((size_t)ND * 256 * 2);
    unsigned short* Ps   = (unsigned short*)alloc((size_t)NS * 256 * 2);
    unsigned short* Pd   = (unsigned short*)alloc((size_t)ND * 256 * 2);
    int* cnt_dis = cnt;
    int* cnt_drug = cnt + NS;

    // --- wprep: zero counters + W transposes + decoder-fold composition ---
    WAll wa;
    wa.w1[0] = Wl1_ds; wa.w1[1] = Wr1_ds; wa.w1[2] = Wl1_sd; wa.w1[3] = Wr1_sd;
    wa.w2[0] = Wl2_ds; wa.w2[1] = Wr2_ds; wa.w2[2] = Wl2_sd; wa.w2[3] = Wr2_sd;
    wa.wdec1 = Wdec1; wa.bl2_ds = bl2_ds; wa.bl2_sd = bl2_sd;
    wprep<<<WPREP_BLKS, 256, 0, stream>>>(cnt, wa, Wt, cbuf);

    // --- mega: rank atomics || layer-1 GEMMs (S.(X@W) factorization) ---
    mega<<<MEGA_BLKS, 256, 0, stream>>>(esrc, edst, cnt_drug, cnt_dis, rank_sd, rank_ds,
                                        x_drug, x_dis, Wt, PA0, RA3, PB2, RB1);

    // --- CSR finish ---
    scan_part<<<SCAN_BLK, 256, 0, stream>>>(cnt, bsum);
    scan_top<<<1, 64, 0, stream>>>(bsum, SCAN_BLK);
    scan_emit<<<SCAN_BLK, 256, 0, stream>>>(cnt, bsum, row_dis, row_drug, inv_dis, inv_drug);
    place_kernel<<<(NE + 255) / 256, 256, 0, stream>>>(esrc, edst, row_drug, row_dis,
                                                       rank_sd, rank_ds, val_sd, val_ds, NE);

    const int AGG_GRID = (NTOT + 3) / 4;

    // --- layer 1: zs1 = relu(agg(PA0) + RB1 + b), zd1 = relu(agg(PB2) + RA3 + b) ---
    agg_fused<<<AGG_GRID, 256, 0, stream>>>(PA0, PB2, row_dis, row_drug, val_ds, val_sd,
                                            inv_dis, inv_drug, RB1, RA3, bl1_ds, bl1_sd,
                                            zs1, zd1, 1);

    // --- layer 2 + decoder fold GEMMs ---
    unsigned short* G1 = PA0;
    unsigned short* G4 = RA3;
    unsigned short* G2 = PB2;
    unsigned short* G3 = RB1;
    {
        Seg1 a = { zd1, Wt + (size_t)4 * 65536, G1, ND, 391 };
        Seg1 b = { zs1, Wt + (size_t)5 * 65536, G2, NS, 235 };
        Seg1 c = { zs1, Wt + (size_t)6 * 65536, G3, NS, 235 };
        Seg1 d = { zd1, Wt + (size_t)7 * 65536, G4, ND, 391 };
        dim3 grid(391 + 235 + 235 + 391, 2);
        gemm_lds4<<<grid, 256, 0, stream>>>(a, b, c, d);
    }

    // --- Ps = agg(G1) + G2 + cb_s ; Pd = agg(G3) + G4 + cb_d ---
    agg_fused<<<AGG_GRID, 256, 0, stream>>>(G1, G3, row_dis, row_drug, val_ds, val_sd,
                                            inv_dis, inv_drug, G2, G4, cbuf, cbuf + 256,
                                            Ps, Pd, 0);

    // --- edge decoder ---
    dec_edge<<<(EL + 7) / 8, 256, 0, stream>>>(Pd, Ps, lrow, lcol, bdec1, Wdec2, bdec2, outp, EL);
}